// Round 3
// baseline (440.556 us; speedup 1.0000x reference)
//
#include <hip/hip_runtime.h>
#include <math.h>

#define DCOLS 4096
#define TPB   256
#define NJ    4            // float4 loads per thread
#define VPT   16           // values per thread
#define KSEL  64
#define CAP   512          // max candidate-list size for the fast path

#define PIV0  2.0f         // P(z>2.0)=0.02275 -> E[count]=93, sd 9.6; P(count<64)~9e-4
#define PIV1  1.55f        // P(z>1.55)=0.0606 -> E[count]=248, sd 15; never <64 in practice

typedef float v4f __attribute__((ext_vector_type(4)));

// Monotone map: larger float <=> larger unsigned
__device__ __forceinline__ unsigned f2ord(float f) {
    unsigned b = __float_as_uint(f);
    return (b & 0x80000000u) ? ~b : (b | 0x80000000u);
}

// Block-wide sum; s4 is a 4-entry LDS scratch. Two barriers. (fallback path only)
__device__ __forceinline__ unsigned block_reduce_sum(unsigned x, unsigned* s4, int t) {
    #pragma unroll
    for (int o = 32; o; o >>= 1) x += __shfl_xor(x, o);
    if ((t & 63) == 0) s4[t >> 6] = x;
    __syncthreads();
    unsigned r = s4[0] + s4[1] + s4[2] + s4[3];
    __syncthreads();
    return r;
}

__global__ __launch_bounds__(TPB) void topk_sigmoid_kernel(
    const float* __restrict__ x, float* __restrict__ out)
{
    const int row  = blockIdx.x;
    const int t    = threadIdx.x;
    const int w    = t >> 6;
    const int lane = t & 63;
    const float* xr   = x   + (size_t)row * DCOLS;
    float*       outr = out + (size_t)row * DCOLS;

    __shared__ unsigned long long cand_key[CAP];
    __shared__ unsigned s_cnt[8];
    __shared__ unsigned s_red[4];
    __shared__ unsigned s_top;
    __shared__ unsigned long long s_Tkey;

    // ---- load 16 elements as 4x float4, fully coalesced ----
    float fv[VPT];
    #pragma unroll
    for (int j = 0; j < NJ; ++j) {
        v4f v = reinterpret_cast<const v4f*>(xr)[t + TPB * j];
        #pragma unroll
        for (int c = 0; c < 4; ++c) fv[4*j + c] = v[c];
    }

    // ---- count above 2 pivots: v_cmp + s_bcnt1, wave-uniform scalar result ----
    unsigned c0 = 0, c1 = 0;
    #pragma unroll
    for (int i = 0; i < VPT; ++i) {
        c0 += (unsigned)__popcll(__ballot(fv[i] > PIV0));
        c1 += (unsigned)__popcll(__ballot(fv[i] > PIV1));
    }
    if (lane == 0) { s_cnt[w] = c0; s_cnt[4 + w] = c1; }
    if (t == 0)    s_top = 0;
    __syncthreads();

    const unsigned tot0 = s_cnt[0] + s_cnt[1] + s_cnt[2] + s_cnt[3];
    const unsigned tot1 = s_cnt[4] + s_cnt[5] + s_cnt[6] + s_cnt[7];

    float piv = PIV0;
    bool  fast = true;
    if (tot0 >= KSEL && tot0 <= CAP)      piv = PIV0;
    else if (tot1 >= KSEL && tot1 <= CAP) piv = PIV1;
    else                                  fast = false;

    if (fast) {
        // ---- compact candidates (atomic-optimizer wave-aggregates this) ----
        #pragma unroll
        for (int i = 0; i < VPT; ++i) {
            if (fv[i] > piv) {
                const unsigned pos = atomicAdd(&s_top, 1u);
                const unsigned gi  = 4u*t + 1024u*(i >> 2) + (i & 3);
                cand_key[pos] = ((unsigned long long)f2ord(fv[i]) << 32)
                              | (unsigned)(~gi);
            }
        }
        __syncthreads();
        const unsigned E = s_top;   // in [KSEL, CAP]
        // exact rank-(K-1): all active lanes stream the same cand_key[e] (broadcast)
        for (unsigned jj = t; jj < E; jj += TPB) {
            const unsigned long long mk = cand_key[jj];
            unsigned r = 0;
            for (unsigned e = 0; e < E; ++e)
                r += (cand_key[e] > mk) ? 1u : 0u;
            if (r == KSEL - 1) s_Tkey = mk;          // exactly one writer
        }
        __syncthreads();
    } else {
        // ---- exact fallback (arbitrary data): count-based binary search ----
        unsigned u[VPT];
        #pragma unroll
        for (int i = 0; i < VPT; ++i) u[i] = f2ord(fv[i]);
        unsigned long long lo = 0, hi = 0xFFFFFFFFull;
        while (lo < hi) {
            const unsigned mid = (unsigned)((lo + hi + 1ull) >> 1);
            unsigned c = 0;
            #pragma unroll
            for (int i = 0; i < VPT; ++i) c += (u[i] >= mid) ? 1u : 0u;
            c = block_reduce_sum(c, s_red, t);
            if (c >= KSEL) lo = mid; else hi = mid - 1ull;
        }
        const unsigned Tu = (unsigned)lo;
        unsigned cgt = 0;
        #pragma unroll
        for (int i = 0; i < VPT; ++i) cgt += (u[i] > Tu) ? 1u : 0u;
        cgt = block_reduce_sum(cgt, s_red, t);
        const unsigned remk = KSEL - cgt;            // in [1, KSEL]
        unsigned ilo = 0, ihi = DCOLS - 1;
        while (ilo < ihi) {
            const unsigned mid = (ilo + ihi) >> 1;
            unsigned c = 0;
            #pragma unroll
            for (int i = 0; i < VPT; ++i) {
                const unsigned gi = 4u*t + 1024u*(i >> 2) + (i & 3);
                c += (u[i] == Tu && gi <= mid) ? 1u : 0u;
            }
            c = block_reduce_sum(c, s_red, t);
            if (c >= remk) ihi = mid; else ilo = mid + 1;
        }
        if (t == 0) s_Tkey = ((unsigned long long)Tu << 32) | (unsigned)(~ilo);
        __syncthreads();
    }

    // ---- decode threshold (value, tie-index) from the winning key ----
    const unsigned long long Tkey = s_Tkey;
    const unsigned hi32 = (unsigned)(Tkey >> 32);
    const unsigned Ti   = ~((unsigned)Tkey);
    const unsigned tb   = (hi32 & 0x80000000u) ? (hi32 & 0x7FFFFFFFu) : ~hi32;
    const float    Tf   = __uint_as_float(tb);

    // ---- emit: sigmoid for selected, 0 otherwise; nontemporal float4 stores ----
    #pragma unroll
    for (int j = 0; j < NJ; ++j) {
        v4f o;
        #pragma unroll
        for (int c = 0; c < 4; ++c) {
            const int i = 4*j + c;
            const unsigned gi = 4u*t + 1024u*j + c;
            const bool inc = (fv[i] > Tf) || (fv[i] == Tf && gi <= Ti);
            const float e  = __expf(-fv[i]);
            o[c] = inc ? __builtin_amdgcn_rcpf(1.0f + e) : 0.0f;
        }
        __builtin_nontemporal_store(o, reinterpret_cast<v4f*>(outr) + t + TPB * j);
    }
}

extern "C" void kernel_launch(void* const* d_in, const int* in_sizes, int n_in,
                              void* d_out, int out_size, void* d_ws, size_t ws_size,
                              hipStream_t stream) {
    const float* x  = (const float*)d_in[0];
    float* out      = (float*)d_out;
    const int nrows = in_sizes[0] / DCOLS;   // 16384
    topk_sigmoid_kernel<<<nrows, TPB, 0, stream>>>(x, out);
}

// Round 4
// 428.247 us; speedup vs baseline: 1.0287x; 1.0287x over previous
//
#include <hip/hip_runtime.h>
#include <math.h>

#define DCOLS 4096
#define TPB   256
#define NJ    4            // float4 loads per thread
#define VPT   16           // values per thread
#define KSEL  64
#define CAP   512          // max candidate-list size for the fast path

#define PIV0  2.0f         // P(z>2.0)=0.02275 -> E[cnt]=93, sd 9.6; P(cnt<64)~9e-4
#define PIV1  1.7f         // P(z>1.7)=0.0446  -> E[cnt]=183, sd 13; never <64 in practice

typedef float v4f __attribute__((ext_vector_type(4)));

// Monotone map: larger float <=> larger unsigned
__device__ __forceinline__ unsigned f2ord(float f) {
    unsigned b = __float_as_uint(f);
    return (b & 0x80000000u) ? ~b : (b | 0x80000000u);
}

// Block-wide sum; s4 is a 4-entry LDS scratch. Two barriers. (fallback path only)
__device__ __forceinline__ unsigned block_reduce_sum(unsigned x, unsigned* s4, int t) {
    #pragma unroll
    for (int o = 32; o; o >>= 1) x += __shfl_xor(x, o);
    if ((t & 63) == 0) s4[t >> 6] = x;
    __syncthreads();
    unsigned r = s4[0] + s4[1] + s4[2] + s4[3];
    __syncthreads();
    return r;
}

__global__ __launch_bounds__(TPB, 8) void topk_sigmoid_kernel(
    const float* __restrict__ x, float* __restrict__ out)
{
    const int row  = blockIdx.x;
    const int t    = threadIdx.x;
    const int w    = t >> 6;
    const int lane = t & 63;
    const float* xr   = x   + (size_t)row * DCOLS;
    float*       outr = out + (size_t)row * DCOLS;

    __shared__ unsigned long long cand_key[CAP];
    __shared__ unsigned s_cnt[8];       // [pivot][wave]
    __shared__ unsigned s_red[4];
    __shared__ unsigned long long s_Tkey;

    // ---- load 16 elements as 4x float4, fully coalesced ----
    float fv[VPT];
    #pragma unroll
    for (int j = 0; j < NJ; ++j) {
        v4f v = reinterpret_cast<const v4f*>(xr)[t + TPB * j];
        #pragma unroll
        for (int c = 0; c < 4; ++c) fv[4*j + c] = v[c];
    }

    // ---- per-wave counts above 2 pivots: v_cmp + s_bcnt1 only ----
    unsigned c0 = 0, c1 = 0;
    #pragma unroll
    for (int i = 0; i < VPT; ++i) {
        c0 += (unsigned)__popcll(__ballot(fv[i] > PIV0));
        c1 += (unsigned)__popcll(__ballot(fv[i] > PIV1));
    }
    if (lane == 0) { s_cnt[w] = c0; s_cnt[4 + w] = c1; }
    __syncthreads();

    const unsigned w0[4] = {s_cnt[0], s_cnt[1], s_cnt[2], s_cnt[3]};
    const unsigned w1[4] = {s_cnt[4], s_cnt[5], s_cnt[6], s_cnt[7]};
    const unsigned tot0 = w0[0] + w0[1] + w0[2] + w0[3];
    const unsigned tot1 = w1[0] + w1[1] + w1[2] + w1[3];

    float piv; bool fast = true; unsigned wbase, E;
    if (tot0 >= KSEL && tot0 <= CAP) {
        piv = PIV0; E = tot0;
        wbase = (w > 0 ? w0[0] : 0u) + (w > 1 ? w0[1] : 0u) + (w > 2 ? w0[2] : 0u);
    } else if (tot1 >= KSEL && tot1 <= CAP) {
        piv = PIV1; E = tot1;
        wbase = (w > 0 ? w1[0] : 0u) + (w > 1 ? w1[1] : 0u) + (w > 2 ? w1[2] : 0u);
    } else {
        fast = false; piv = 0.f; E = 0; wbase = 0;
    }

    if (fast) {
        // ---- zero-atomic compaction: ballot-prefix positions ----
        const unsigned long long lml = (1ull << lane) - 1ull;
        #pragma unroll
        for (int i = 0; i < VPT; ++i) {
            const bool pred = fv[i] > piv;
            const unsigned long long mask = __ballot(pred);
            if (pred) {
                const unsigned pos = wbase + (unsigned)__popcll(mask & lml);
                const unsigned gi  = 4u*t + 1024u*(i >> 2) + (i & 3);
                cand_key[pos] = ((unsigned long long)f2ord(fv[i]) << 32)
                              | (unsigned)(~gi);
            }
            wbase += (unsigned)__popcll(mask);
        }
        __syncthreads();
        // ---- exact rank-(K-1): broadcast LDS reads, E in [64, 512] ----
        for (unsigned jj = t; jj < E; jj += TPB) {
            const unsigned long long mk = cand_key[jj];
            unsigned r = 0;
            for (unsigned e = 0; e < E; ++e)
                r += (cand_key[e] > mk) ? 1u : 0u;
            if (r == KSEL - 1) s_Tkey = mk;          // exactly one writer
        }
        __syncthreads();
    } else {
        // ---- exact fallback (arbitrary data): count-based binary search ----
        unsigned long long lo = 0, hi = 0xFFFFFFFFull;
        while (lo < hi) {
            const unsigned mid = (unsigned)((lo + hi + 1ull) >> 1);
            unsigned c = 0;
            #pragma unroll
            for (int i = 0; i < VPT; ++i) c += (f2ord(fv[i]) >= mid) ? 1u : 0u;
            c = block_reduce_sum(c, s_red, t);
            if (c >= KSEL) lo = mid; else hi = mid - 1ull;
        }
        const unsigned Tu = (unsigned)lo;
        unsigned cgt = 0;
        #pragma unroll
        for (int i = 0; i < VPT; ++i) cgt += (f2ord(fv[i]) > Tu) ? 1u : 0u;
        cgt = block_reduce_sum(cgt, s_red, t);
        const unsigned remk = KSEL - cgt;            // in [1, KSEL]
        unsigned ilo = 0, ihi = DCOLS - 1;
        while (ilo < ihi) {
            const unsigned mid = (ilo + ihi) >> 1;
            unsigned c = 0;
            #pragma unroll
            for (int i = 0; i < VPT; ++i) {
                const unsigned gi = 4u*t + 1024u*(i >> 2) + (i & 3);
                c += (f2ord(fv[i]) == Tu && gi <= mid) ? 1u : 0u;
            }
            c = block_reduce_sum(c, s_red, t);
            if (c >= remk) ihi = mid; else ilo = mid + 1;
        }
        if (t == 0) s_Tkey = ((unsigned long long)Tu << 32) | (unsigned)(~ilo);
        __syncthreads();
    }

    // ---- decode threshold (value, tie-index) from the winning key ----
    const unsigned long long Tkey = s_Tkey;
    const unsigned hi32 = (unsigned)(Tkey >> 32);
    const unsigned Ti   = ~((unsigned)Tkey);
    const unsigned tb   = (hi32 & 0x80000000u) ? (hi32 & 0x7FFFFFFFu) : ~hi32;
    const float    Tf   = __uint_as_float(tb);

    // ---- emit: sigmoid for selected, 0 otherwise; coalesced float4 stores ----
    #pragma unroll
    for (int j = 0; j < NJ; ++j) {
        v4f o;
        #pragma unroll
        for (int c = 0; c < 4; ++c) {
            const int i = 4*j + c;
            const unsigned gi = 4u*t + 1024u*j + c;
            const bool inc = (fv[i] > Tf) || (fv[i] == Tf && gi <= Ti);
            const float e  = __expf(-fv[i]);
            o[c] = inc ? __builtin_amdgcn_rcpf(1.0f + e) : 0.0f;
        }
        reinterpret_cast<v4f*>(outr)[t + TPB * j] = o;
    }
}

extern "C" void kernel_launch(void* const* d_in, const int* in_sizes, int n_in,
                              void* d_out, int out_size, void* d_ws, size_t ws_size,
                              hipStream_t stream) {
    const float* x  = (const float*)d_in[0];
    float* out      = (float*)d_out;
    const int nrows = in_sizes[0] / DCOLS;   // 16384
    topk_sigmoid_kernel<<<nrows, TPB, 0, stream>>>(x, out);
}